// Round 1
// baseline (604.403 us; speedup 1.0000x reference)
//
#include <hip/hip_runtime.h>
#include <hip/hip_bf16.h>

// HyperNet fused forward.
// Key algebraic collapse:
//   logits = concat(client_enc, mean_update) @ comb_w + comb_b
//          = h1 @ (enc_w2 @ comb_top)  +  h2 @ (pol_w3 @ comb_bot)  +  (b3 @ comb_bot + comb_b)
// with h1 = relu(enc @ enc_w1) [N,64], h2 = relu(relu(mean@pol_w1+b1)@pol_w2+b2) [N,32].
// This turns a 68.7 GF K=2048 GEMM into a 3.2 GF K=96 GEMM (fp32 thresholds easily met).

#define N_CLIENTS 16384
#define P 1024
#define IN_DIM 512
#define ROWS 8          // client rows per block

// ---------------------------------------------------------------------------
// Kernel 1: fused-weight precompute into d_ws.
// fused layout: [0..63]   fused_top  = enc_w2 @ comb_w[0:1024]      (64 x 1024)
//               [64..95]  fused_bot  = pol_w3 @ comb_w[1024:2048]   (32 x 1024)
//               [96]      fused_bias = pol_b3 @ comb_w[1024:2048] + comb_b (1024)
// grid (4, 13): x = 256-column chunk, y: 0..7 top rows, 8..11 bot rows, 12 bias.
// ---------------------------------------------------------------------------
__global__ __launch_bounds__(256) void precompute_fused(
    const float* __restrict__ enc_w2,   // [64][1024]
    const float* __restrict__ pol_w3,   // [32][1024]
    const float* __restrict__ pol_b3,   // [1024]
    const float* __restrict__ comb_w,   // [2048][1024]
    const float* __restrict__ comb_b,   // [1024]
    float* __restrict__ fused)          // [97][1024]
{
    __shared__ __attribute__((aligned(16))) float s_w[8][1024];

    const int t = threadIdx.x;
    const int j = blockIdx.x * 256 + t;
    const int by = blockIdx.y;

    const float* wsrc;
    int nr, kbase, outbase;
    if (by < 8)       { wsrc = enc_w2 + by * 8 * 1024;        nr = 8; kbase = 0;    outbase = by * 8; }
    else if (by < 12) { wsrc = pol_w3 + (by - 8) * 8 * 1024;  nr = 8; kbase = 1024; outbase = 64 + (by - 8) * 8; }
    else              { wsrc = pol_b3;                        nr = 1; kbase = 1024; outbase = 96; }

    float* s_flat = &s_w[0][0];
    for (int i = t; i < nr * 1024; i += 256) s_flat[i] = wsrc[i];
    __syncthreads();

    float acc[8];
    #pragma unroll
    for (int r = 0; r < 8; ++r) acc[r] = 0.f;

    const float* cw = comb_w + (size_t)kbase * 1024 + j;
    #pragma unroll 4
    for (int k = 0; k < 1024; ++k) {
        const float c = cw[(size_t)k * 1024];
        #pragma unroll
        for (int r = 0; r < 8; ++r) acc[r] = fmaf(s_w[r][k], c, acc[r]);
    }

    if (by == 12) {
        fused[96 * 1024 + j] = acc[0] + comb_b[j];
    } else {
        #pragma unroll
        for (int r = 0; r < 8; ++r) fused[(outbase + r) * 1024 + j] = acc[r];
    }
}

// ---------------------------------------------------------------------------
// Kernel 2: main fused forward. One block = 8 client rows, 256 threads.
// ---------------------------------------------------------------------------
__global__ __launch_bounds__(256) void hypernet_main(
    const float* __restrict__ encoding,  // [N][512]
    const float* __restrict__ mean,      // [N][1024]
    const float* __restrict__ enc_w1,    // [512][64]
    const float* __restrict__ pol_w1,    // [1024][32]
    const float* __restrict__ pol_b1,    // [32]
    const float* __restrict__ pol_w2,    // [32][32]
    const float* __restrict__ pol_b2,    // [32]
    const float* __restrict__ eps,       // [N][1024]
    const float* __restrict__ fused,     // [97][1024]
    float* __restrict__ out_sample,      // [N][1024]
    float* __restrict__ out_logprob,     // [N]
    float* __restrict__ out_entropy)     // [N]
{
    __shared__ __attribute__((aligned(16))) float s_enc[ROWS][IN_DIM];   // 16 KB
    __shared__ __attribute__((aligned(16))) float s_mean[ROWS][P];       // 32 KB
    __shared__ __attribute__((aligned(16))) float s_h1[ROWS][64];        // 2 KB
    __shared__ __attribute__((aligned(16))) float s_t1[ROWS][32];
    __shared__ __attribute__((aligned(16))) float s_t2[ROWS][32];
    __shared__ float s_red[4][ROWS];

    const int t = threadIdx.x;
    const long r0 = (long)blockIdx.x * ROWS;

    // ---- stage encoding + mean tiles (contiguous rows -> pure float4 copy)
    {
        const float4* ev = (const float4*)(encoding + r0 * IN_DIM);
        float4* se = (float4*)&s_enc[0][0];
        #pragma unroll
        for (int i = 0; i < (ROWS * IN_DIM / 4) / 256; ++i) se[t + 256 * i] = ev[t + 256 * i];
        const float4* mv = (const float4*)(mean + r0 * P);
        float4* sm = (float4*)&s_mean[0][0];
        #pragma unroll
        for (int i = 0; i < (ROWS * P / 4) / 256; ++i) sm[t + 256 * i] = mv[t + 256 * i];
    }
    __syncthreads();

    // ---- phase 1: t1 = relu(mean @ pol_w1 + b1)   thread (r = t>>5, o = t&31)
    {
        const int r = t >> 5, o = t & 31;
        float acc = pol_b1[o];
        const float* mrow = s_mean[r];
        #pragma unroll 4
        for (int k = 0; k < P; k += 4) {
            const float4 m4 = *(const float4*)&mrow[k];
            acc = fmaf(m4.x, pol_w1[(k + 0) * 32 + o], acc);
            acc = fmaf(m4.y, pol_w1[(k + 1) * 32 + o], acc);
            acc = fmaf(m4.z, pol_w1[(k + 2) * 32 + o], acc);
            acc = fmaf(m4.w, pol_w1[(k + 3) * 32 + o], acc);
        }
        s_t1[r][o] = fmaxf(acc, 0.f);
    }
    __syncthreads();

    // ---- phase 2: t2 = relu(t1 @ pol_w2 + b2)
    {
        const int r = t >> 5, o = t & 31;
        float acc = pol_b2[o];
        #pragma unroll
        for (int k = 0; k < 32; ++k) acc = fmaf(s_t1[r][k], pol_w2[k * 32 + o], acc);
        s_t2[r][o] = fmaxf(acc, 0.f);
    }

    // ---- phase 3: h1 = relu(enc @ enc_w1)   thread (o = t&63, rows rp and rp+4)
    {
        const int o = t & 63, rp = t >> 6;
        float a0 = 0.f, a1 = 0.f;
        #pragma unroll 4
        for (int k = 0; k < IN_DIM; k += 4) {
            const float4 e0 = *(const float4*)&s_enc[rp][k];
            const float4 e1 = *(const float4*)&s_enc[rp + 4][k];
            const float w0 = enc_w1[(k + 0) * 64 + o];
            const float w1 = enc_w1[(k + 1) * 64 + o];
            const float w2 = enc_w1[(k + 2) * 64 + o];
            const float w3 = enc_w1[(k + 3) * 64 + o];
            a0 = fmaf(e0.x, w0, a0); a1 = fmaf(e1.x, w0, a1);
            a0 = fmaf(e0.y, w1, a0); a1 = fmaf(e1.y, w1, a1);
            a0 = fmaf(e0.z, w2, a0); a1 = fmaf(e1.z, w2, a1);
            a0 = fmaf(e0.w, w3, a0); a1 = fmaf(e1.w, w3, a1);
        }
        s_h1[rp][o]     = fmaxf(a0, 0.f);
        s_h1[rp + 4][o] = fmaxf(a1, 0.f);
    }
    __syncthreads();

    // ---- phase 4: logits = h1 @ fused_top + t2 @ fused_bot + fused_bias; epilogue
    const float* ft    = fused;
    const float* fbm   = fused + 64 * 1024;
    const float* fbias = fused + 96 * 1024;

    float acc[4][ROWS];   // [column-chunk][row]
    #pragma unroll
    for (int c = 0; c < 4; ++c) {
        const float b = fbias[t + 256 * c];
        #pragma unroll
        for (int r = 0; r < ROWS; ++r) acc[c][r] = b;
    }

    #pragma unroll 2
    for (int i = 0; i < 64; i += 4) {
        float ha[ROWS][4];
        #pragma unroll
        for (int r = 0; r < ROWS; ++r) {
            const float4 v = *(const float4*)&s_h1[r][i];
            ha[r][0] = v.x; ha[r][1] = v.y; ha[r][2] = v.z; ha[r][3] = v.w;
        }
        #pragma unroll
        for (int q = 0; q < 4; ++q) {
            #pragma unroll
            for (int c = 0; c < 4; ++c) {
                const float w = ft[(i + q) * 1024 + t + 256 * c];
                #pragma unroll
                for (int r = 0; r < ROWS; ++r) acc[c][r] = fmaf(ha[r][q], w, acc[c][r]);
            }
        }
    }
    #pragma unroll 2
    for (int i = 0; i < 32; i += 4) {
        float ha[ROWS][4];
        #pragma unroll
        for (int r = 0; r < ROWS; ++r) {
            const float4 v = *(const float4*)&s_t2[r][i];
            ha[r][0] = v.x; ha[r][1] = v.y; ha[r][2] = v.z; ha[r][3] = v.w;
        }
        #pragma unroll
        for (int q = 0; q < 4; ++q) {
            #pragma unroll
            for (int c = 0; c < 4; ++c) {
                const float w = fbm[(i + q) * 1024 + t + 256 * c];
                #pragma unroll
                for (int r = 0; r < ROWS; ++r) acc[c][r] = fmaf(ha[r][q], w, acc[c][r]);
            }
        }
    }

    // epilogue: sigmoid -> sample -> clip -> sq accumulation
    float sq[ROWS];
    #pragma unroll
    for (int r = 0; r < ROWS; ++r) sq[r] = 0.f;

    #pragma unroll
    for (int c = 0; c < 4; ++c) {
        const int j = t + 256 * c;
        #pragma unroll
        for (int r = 0; r < ROWS; ++r) {
            const float x = acc[c][r];
            const float m = 1.f / (1.f + __expf(-x));
            const float e = eps[(r0 + r) * P + j];
            float s = fmaf(0.22360679774997896f, e, m);  // sqrt(0.05)
            s = fminf(fmaxf(s, 0.f), 1.f);
            out_sample[(r0 + r) * P + j] = s;
            const float d = s - m;
            sq[r] = fmaf(d, d, sq[r]);
        }
    }

    // per-row block reduction: wave shuffle then cross-wave via LDS
    #pragma unroll
    for (int r = 0; r < ROWS; ++r) {
        float v = sq[r];
        v += __shfl_xor(v, 1);
        v += __shfl_xor(v, 2);
        v += __shfl_xor(v, 4);
        v += __shfl_xor(v, 8);
        v += __shfl_xor(v, 16);
        v += __shfl_xor(v, 32);
        if ((t & 63) == 0) s_red[t >> 6][r] = v;
    }
    __syncthreads();
    if (t < ROWS) {
        const float v = s_red[0][t] + s_red[1][t] + s_red[2][t] + s_red[3][t];
        // logprob = -0.5/VAR * sum - 0.5*k*(LOG_2PI + log(VAR))
        out_logprob[r0 + t] = fmaf(-10.f, v, 592.8218660580586f);
        // entropy = 0.5*k*(LOG_2PI + log(VAR) + 1)
        out_entropy[r0 + t] = -80.82186605805855f;
    }
}

extern "C" void kernel_launch(void* const* d_in, const int* in_sizes, int n_in,
                              void* d_out, int out_size, void* d_ws, size_t ws_size,
                              hipStream_t stream) {
    const float* encoding = (const float*)d_in[0];
    const float* mean     = (const float*)d_in[1];
    const float* enc_w1   = (const float*)d_in[2];
    const float* enc_w2   = (const float*)d_in[3];
    const float* pol_w1   = (const float*)d_in[4];
    const float* pol_b1   = (const float*)d_in[5];
    const float* pol_w2   = (const float*)d_in[6];
    const float* pol_b2   = (const float*)d_in[7];
    const float* pol_w3   = (const float*)d_in[8];
    const float* pol_b3   = (const float*)d_in[9];
    const float* comb_w   = (const float*)d_in[10];
    const float* comb_b   = (const float*)d_in[11];
    const float* eps      = (const float*)d_in[12];

    float* fused = (float*)d_ws;                     // 97*1024 floats = 397 KB
    float* out_sample  = (float*)d_out;
    float* out_logprob = out_sample + (size_t)N_CLIENTS * P;
    float* out_entropy = out_logprob + N_CLIENTS;

    dim3 gpre(4, 13);
    precompute_fused<<<gpre, 256, 0, stream>>>(enc_w2, pol_w3, pol_b3, comb_w, comb_b, fused);

    hypernet_main<<<N_CLIENTS / ROWS, 256, 0, stream>>>(
        encoding, mean, enc_w1, pol_w1, pol_b1, pol_w2, pol_b2, eps, fused,
        out_sample, out_logprob, out_entropy);
}

// Round 2
// 438.770 us; speedup vs baseline: 1.3775x; 1.3775x over previous
//
#include <hip/hip_runtime.h>
#include <hip/hip_bf16.h>

// HyperNet fused forward, v2: 4-stage pipeline, all stages sized for 256 CUs.
//
// Algebraic collapse (unchanged from R1):
//   logits = h1 @ (enc_w2 @ comb_top) + h2 @ (pol_w3 @ comb_bot) + (pol_b3 @ comb_bot + comb_b)
//   h1 = relu(enc @ enc_w1) [N,64],  h2 = relu(relu(mean@pol_w1+b1)@pol_w2+b2) [N,32]
//
// R1 failure modes fixed here:
//   - precompute had 52 blocks + 1024-long serial chains (257 us) -> k-split x8, 416 blocks, atomics
//   - main kernel 53.7KB LDS -> 2 blocks/CU, phase serialization (347 us) -> split into
//     compute_h (no big LDS, 4 rows/thread) + logits_epilogue (6KB LDS, 16x4 register tile)

#define N_CLIENTS 16384
#define P 1024
#define IN_DIM 512

// ---------------------------------------------------------------------------
// Kernel 1: fused-weight precompute. fused[97][1024] in ws (pre-zeroed).
//   rows 0..63  = enc_w2 @ comb_w[0:1024]
//   rows 64..95 = pol_w3 @ comb_w[1024:2048]
//   row  96     = pol_b3 @ comb_w[1024:2048] + comb_b
// grid (4, 13, 8): x = 256-col chunk, y = row-group, z = k-chunk of 128.
// ---------------------------------------------------------------------------
__global__ __launch_bounds__(256) void precompute_fused(
    const float* __restrict__ enc_w2,   // [64][1024]
    const float* __restrict__ pol_w3,   // [32][1024]
    const float* __restrict__ pol_b3,   // [1024]
    const float* __restrict__ comb_w,   // [2048][1024]
    const float* __restrict__ comb_b,   // [1024]
    float* __restrict__ fused)          // [97][1024]
{
    __shared__ __attribute__((aligned(16))) float s_w[8][128];

    const int t = threadIdx.x;
    const int j = blockIdx.x * 256 + t;
    const int by = blockIdx.y;
    const int kz = blockIdx.z;          // k-chunk: [kz*128, kz*128+128)

    const float* wsrc;
    int nr, kbase, outbase;
    if (by < 8)       { wsrc = enc_w2 + by * 8 * 1024;        nr = 8; kbase = 0;    outbase = by * 8; }
    else if (by < 12) { wsrc = pol_w3 + (by - 8) * 8 * 1024;  nr = 8; kbase = 1024; outbase = 64 + (by - 8) * 8; }
    else              { wsrc = pol_b3;                        nr = 1; kbase = 1024; outbase = 96; }

    for (int i = t; i < nr * 128; i += 256) {
        const int r = i >> 7, kk = i & 127;
        s_w[r][kk] = wsrc[r * 1024 + kz * 128 + kk];
    }
    __syncthreads();

    float acc[8];
    #pragma unroll
    for (int r = 0; r < 8; ++r) acc[r] = 0.f;

    const float* cw = comb_w + ((size_t)kbase + kz * 128) * 1024 + j;
    #pragma unroll 4
    for (int k = 0; k < 128; ++k) {
        const float c = cw[(size_t)k * 1024];
        #pragma unroll
        for (int r = 0; r < 8; ++r) acc[r] = fmaf(s_w[r][k], c, acc[r]);
    }

    if (by == 12) {
        float v = acc[0] + (kz == 0 ? comb_b[j] : 0.f);
        atomicAdd(&fused[96 * 1024 + j], v);
    } else {
        #pragma unroll
        for (int r = 0; r < 8; ++r) atomicAdd(&fused[(outbase + r) * 1024 + j], acc[r]);
    }
}

// ---------------------------------------------------------------------------
// Kernel 2: h1h2[N][96] = [relu(enc@enc_w1) | relu(relu(mean@pol_w1+b1)@pol_w2+b2)]
// grid (1024, 2): y=0 -> h1 path (16 rows/block), y=1 -> h2 path (32 rows/block, x<512)
// 4 rows per thread so each weight load feeds 4 FMAs.
// ---------------------------------------------------------------------------
__global__ __launch_bounds__(256) void compute_h(
    const float* __restrict__ encoding,  // [N][512]
    const float* __restrict__ mean,      // [N][1024]
    const float* __restrict__ enc_w1,    // [512][64]
    const float* __restrict__ pol_w1,    // [1024][32]
    const float* __restrict__ pol_b1,    // [32]
    const float* __restrict__ pol_w2,    // [32][32]
    const float* __restrict__ pol_b2,    // [32]
    float* __restrict__ h1h2)            // [N][96]
{
    __shared__ float s_t1[32][32];
    const int t = threadIdx.x;

    if (blockIdx.y == 0) {
        // ---- h1 path: rows r0 .. r0+15, thread (o = t&63, rg = t>>6) -> rows rg*4..rg*4+3
        const long r0 = (long)blockIdx.x * 16;
        const int o = t & 63, rg = t >> 6;
        const float* e = encoding + (r0 + rg * 4) * IN_DIM;
        float a0 = 0.f, a1 = 0.f, a2 = 0.f, a3 = 0.f;
        #pragma unroll 2
        for (int k = 0; k < IN_DIM; k += 4) {
            const float4 m0 = *(const float4*)(e + k);
            const float4 m1 = *(const float4*)(e + IN_DIM + k);
            const float4 m2 = *(const float4*)(e + 2 * IN_DIM + k);
            const float4 m3 = *(const float4*)(e + 3 * IN_DIM + k);
            const float w0 = enc_w1[(k + 0) * 64 + o];
            const float w1 = enc_w1[(k + 1) * 64 + o];
            const float w2 = enc_w1[(k + 2) * 64 + o];
            const float w3 = enc_w1[(k + 3) * 64 + o];
            a0 = fmaf(m0.x, w0, a0); a0 = fmaf(m0.y, w1, a0); a0 = fmaf(m0.z, w2, a0); a0 = fmaf(m0.w, w3, a0);
            a1 = fmaf(m1.x, w0, a1); a1 = fmaf(m1.y, w1, a1); a1 = fmaf(m1.z, w2, a1); a1 = fmaf(m1.w, w3, a1);
            a2 = fmaf(m2.x, w0, a2); a2 = fmaf(m2.y, w1, a2); a2 = fmaf(m2.z, w2, a2); a2 = fmaf(m2.w, w3, a2);
            a3 = fmaf(m3.x, w0, a3); a3 = fmaf(m3.y, w1, a3); a3 = fmaf(m3.z, w2, a3); a3 = fmaf(m3.w, w3, a3);
        }
        float* hp = h1h2 + (r0 + rg * 4) * 96 + o;
        hp[0]   = fmaxf(a0, 0.f);
        hp[96]  = fmaxf(a1, 0.f);
        hp[192] = fmaxf(a2, 0.f);
        hp[288] = fmaxf(a3, 0.f);
    } else {
        // ---- h2 path: rows r0 .. r0+31, thread (o = t&31, rg = t>>5) -> rows rg*4..rg*4+3
        if (blockIdx.x >= 512) return;
        const long r0 = (long)blockIdx.x * 32;
        const int o = t & 31, rg = t >> 5;
        const float* mp = mean + (r0 + rg * 4) * P;
        const float b1v = pol_b1[o];
        float a0 = b1v, a1 = b1v, a2 = b1v, a3 = b1v;
        #pragma unroll 2
        for (int k = 0; k < P; k += 4) {
            const float4 m0 = *(const float4*)(mp + k);
            const float4 m1 = *(const float4*)(mp + P + k);
            const float4 m2 = *(const float4*)(mp + 2 * P + k);
            const float4 m3 = *(const float4*)(mp + 3 * P + k);
            const float w0 = pol_w1[(k + 0) * 32 + o];
            const float w1 = pol_w1[(k + 1) * 32 + o];
            const float w2 = pol_w1[(k + 2) * 32 + o];
            const float w3 = pol_w1[(k + 3) * 32 + o];
            a0 = fmaf(m0.x, w0, a0); a0 = fmaf(m0.y, w1, a0); a0 = fmaf(m0.z, w2, a0); a0 = fmaf(m0.w, w3, a0);
            a1 = fmaf(m1.x, w0, a1); a1 = fmaf(m1.y, w1, a1); a1 = fmaf(m1.z, w2, a1); a1 = fmaf(m1.w, w3, a1);
            a2 = fmaf(m2.x, w0, a2); a2 = fmaf(m2.y, w1, a2); a2 = fmaf(m2.z, w2, a2); a2 = fmaf(m2.w, w3, a2);
            a3 = fmaf(m3.x, w0, a3); a3 = fmaf(m3.y, w1, a3); a3 = fmaf(m3.z, w2, a3); a3 = fmaf(m3.w, w3, a3);
        }
        const int rb = rg * 4;
        s_t1[rb + 0][o] = fmaxf(a0, 0.f);
        s_t1[rb + 1][o] = fmaxf(a1, 0.f);
        s_t1[rb + 2][o] = fmaxf(a2, 0.f);
        s_t1[rb + 3][o] = fmaxf(a3, 0.f);
        __syncthreads();
        const float b2v = pol_b2[o];
        float c0 = b2v, c1 = b2v, c2 = b2v, c3 = b2v;
        #pragma unroll
        for (int k = 0; k < 32; ++k) {
            const float w = pol_w2[k * 32 + o];
            c0 = fmaf(s_t1[rb + 0][k], w, c0);
            c1 = fmaf(s_t1[rb + 1][k], w, c1);
            c2 = fmaf(s_t1[rb + 2][k], w, c2);
            c3 = fmaf(s_t1[rb + 3][k], w, c3);
        }
        float* hp = h1h2 + (r0 + rb) * 96 + 64 + o;
        hp[0]   = fmaxf(c0, 0.f);
        hp[96]  = fmaxf(c1, 0.f);
        hp[192] = fmaxf(c2, 0.f);
        hp[288] = fmaxf(c3, 0.f);
    }
}

// ---------------------------------------------------------------------------
// Kernel 3: logits = h1h2 @ fused[0:96] + fused[96]; sigmoid/sample/logprob.
// grid 1024 blocks x 256 threads. Block = 16 rows x 1024 cols.
// Thread tile: 16 rows x 4 contiguous cols (j0 = t*4). h via broadcast ds_read_b128.
// ---------------------------------------------------------------------------
__global__ __launch_bounds__(256) void logits_epilogue(
    const float* __restrict__ h1h2,    // [N][96]
    const float* __restrict__ fused,   // [97][1024]
    const float* __restrict__ eps,     // [N][1024]
    float* __restrict__ out_sample,    // [N][1024]
    float* __restrict__ out_logprob,   // [N]
    float* __restrict__ out_entropy)   // [N]
{
    __shared__ __attribute__((aligned(16))) float s_h[16][96];   // 6 KB
    __shared__ float s_red[16][4];

    const int t = threadIdx.x;
    const long r0 = (long)blockIdx.x * 16;

    {   // stage 16 h-rows: 384 float4
        const float4* src = (const float4*)(h1h2 + r0 * 96);
        float4* dst = (float4*)&s_h[0][0];
        dst[t] = src[t];
        if (t < 128) dst[256 + t] = src[256 + t];
    }
    __syncthreads();

    const int j0 = t * 4;
    const float* fp = fused + j0;
    const float4 bias = *(const float4*)(fp + 96 * 1024);
    float acc[16][4];
    #pragma unroll
    for (int r = 0; r < 16; ++r) {
        acc[r][0] = bias.x; acc[r][1] = bias.y; acc[r][2] = bias.z; acc[r][3] = bias.w;
    }

    #pragma unroll 2
    for (int k4 = 0; k4 < 24; ++k4) {
        const float* fk = fp + k4 * 4096;
        const float4 w0 = *(const float4*)(fk);
        const float4 w1 = *(const float4*)(fk + 1024);
        const float4 w2 = *(const float4*)(fk + 2048);
        const float4 w3 = *(const float4*)(fk + 3072);
        #pragma unroll
        for (int r = 0; r < 16; ++r) {
            const float4 h = *(const float4*)&s_h[r][k4 * 4];   // broadcast, conflict-free
            acc[r][0] = fmaf(h.x, w0.x, acc[r][0]);
            acc[r][0] = fmaf(h.y, w1.x, acc[r][0]);
            acc[r][0] = fmaf(h.z, w2.x, acc[r][0]);
            acc[r][0] = fmaf(h.w, w3.x, acc[r][0]);
            acc[r][1] = fmaf(h.x, w0.y, acc[r][1]);
            acc[r][1] = fmaf(h.y, w1.y, acc[r][1]);
            acc[r][1] = fmaf(h.z, w2.y, acc[r][1]);
            acc[r][1] = fmaf(h.w, w3.y, acc[r][1]);
            acc[r][2] = fmaf(h.x, w0.z, acc[r][2]);
            acc[r][2] = fmaf(h.y, w1.z, acc[r][2]);
            acc[r][2] = fmaf(h.z, w2.z, acc[r][2]);
            acc[r][2] = fmaf(h.w, w3.z, acc[r][2]);
            acc[r][3] = fmaf(h.x, w0.w, acc[r][3]);
            acc[r][3] = fmaf(h.y, w1.w, acc[r][3]);
            acc[r][3] = fmaf(h.z, w2.w, acc[r][3]);
            acc[r][3] = fmaf(h.w, w3.w, acc[r][3]);
        }
    }

    const float* ep = eps + r0 * P + j0;
    float* sp = out_sample + r0 * P + j0;
    #pragma unroll
    for (int r = 0; r < 16; ++r) {
        const float m0 = 1.f / (1.f + __expf(-acc[r][0]));
        const float m1 = 1.f / (1.f + __expf(-acc[r][1]));
        const float m2 = 1.f / (1.f + __expf(-acc[r][2]));
        const float m3 = 1.f / (1.f + __expf(-acc[r][3]));
        const float4 e = *(const float4*)(ep + r * P);
        const float s0 = fminf(fmaxf(fmaf(0.22360679774997896f, e.x, m0), 0.f), 1.f);
        const float s1 = fminf(fmaxf(fmaf(0.22360679774997896f, e.y, m1), 0.f), 1.f);
        const float s2 = fminf(fmaxf(fmaf(0.22360679774997896f, e.z, m2), 0.f), 1.f);
        const float s3 = fminf(fmaxf(fmaf(0.22360679774997896f, e.w, m3), 0.f), 1.f);
        *(float4*)(sp + r * P) = make_float4(s0, s1, s2, s3);
        const float d0 = s0 - m0, d1 = s1 - m1, d2 = s2 - m2, d3 = s3 - m3;
        float v = fmaf(d0, d0, fmaf(d1, d1, fmaf(d2, d2, d3 * d3)));
        v += __shfl_xor(v, 1);
        v += __shfl_xor(v, 2);
        v += __shfl_xor(v, 4);
        v += __shfl_xor(v, 8);
        v += __shfl_xor(v, 16);
        v += __shfl_xor(v, 32);
        if ((t & 63) == 0) s_red[r][t >> 6] = v;
    }
    __syncthreads();
    if (t < 16) {
        const float v = s_red[t][0] + s_red[t][1] + s_red[t][2] + s_red[t][3];
        out_logprob[r0 + t] = fmaf(-10.f, v, 592.8218660580586f);
        out_entropy[r0 + t] = -80.82186605805855f;
    }
}

extern "C" void kernel_launch(void* const* d_in, const int* in_sizes, int n_in,
                              void* d_out, int out_size, void* d_ws, size_t ws_size,
                              hipStream_t stream) {
    const float* encoding = (const float*)d_in[0];
    const float* mean     = (const float*)d_in[1];
    const float* enc_w1   = (const float*)d_in[2];
    const float* enc_w2   = (const float*)d_in[3];
    const float* pol_w1   = (const float*)d_in[4];
    const float* pol_b1   = (const float*)d_in[5];
    const float* pol_w2   = (const float*)d_in[6];
    const float* pol_b2   = (const float*)d_in[7];
    const float* pol_w3   = (const float*)d_in[8];
    const float* pol_b3   = (const float*)d_in[9];
    const float* comb_w   = (const float*)d_in[10];
    const float* comb_b   = (const float*)d_in[11];
    const float* eps      = (const float*)d_in[12];

    float* fused = (float*)d_ws;                          // 97*1024 floats
    float* h1h2  = fused + 97 * 1024;                     // 16384*96 floats
    float* out_sample  = (float*)d_out;
    float* out_logprob = out_sample + (size_t)N_CLIENTS * P;
    float* out_entropy = out_logprob + N_CLIENTS;

    hipMemsetAsync(fused, 0, 97 * 1024 * sizeof(float), stream);

    dim3 gpre(4, 13, 8);
    precompute_fused<<<gpre, 256, 0, stream>>>(enc_w2, pol_w3, pol_b3, comb_w, comb_b, fused);

    dim3 gh(1024, 2);
    compute_h<<<gh, 256, 0, stream>>>(encoding, mean, enc_w1, pol_w1, pol_b1, pol_w2, pol_b2, h1h2);

    logits_epilogue<<<N_CLIENTS / 16, 256, 0, stream>>>(
        h1h2, fused, eps, out_sample, out_logprob, out_entropy);
}

// Round 3
// 316.924 us; speedup vs baseline: 1.9071x; 1.3845x over previous
//
#include <hip/hip_runtime.h>

// HyperNet fused forward, v3.
// Algebraic collapse (unchanged):
//   logits = h1 @ (enc_w2 @ comb_top) + h2 @ (pol_w3 @ comb_bot) + (pol_b3 @ comb_bot + comb_b)
//   h1 = relu(enc @ enc_w1) [N,64],  h2 = relu(relu(mean@pol_w1+b1)@pol_w2+b2) [N,32]
//
// R2 failure mode: both hot kernels latency-bound (VALUBusy 22%) — wave-uniform 16B
// broadcast loads in compute_h, serialized global w-loads in logits. v3 restructures:
//   compute_h: LDS-tiled GEMM (coalesced A staging, W k-tiles in LDS, inner loop LDS-only)
//   logits:    16 independent global f4 loads per iteration from L2-resident fused matrix

#define N_CLIENTS 16384
#define P 1024
#define IN_DIM 512
#define PAD 40   // LDS row stride (floats) for staged A tiles; mult of 4 for f4 stores

// ---------------------------------------------------------------------------
// Kernel 1: fused-weight precompute (unchanged from R2, ~10 us).
// ---------------------------------------------------------------------------
__global__ __launch_bounds__(256) void precompute_fused(
    const float* __restrict__ enc_w2,   // [64][1024]
    const float* __restrict__ pol_w3,   // [32][1024]
    const float* __restrict__ pol_b3,   // [1024]
    const float* __restrict__ comb_w,   // [2048][1024]
    const float* __restrict__ comb_b,   // [1024]
    float* __restrict__ fused)          // [97][1024]
{
    __shared__ __attribute__((aligned(16))) float s_w[8][128];
    const int t = threadIdx.x;
    const int j = blockIdx.x * 256 + t;
    const int by = blockIdx.y;
    const int kz = blockIdx.z;

    const float* wsrc; int nr, kbase, outbase;
    if (by < 8)       { wsrc = enc_w2 + by * 8 * 1024;        nr = 8; kbase = 0;    outbase = by * 8; }
    else if (by < 12) { wsrc = pol_w3 + (by - 8) * 8 * 1024;  nr = 8; kbase = 1024; outbase = 64 + (by - 8) * 8; }
    else              { wsrc = pol_b3;                        nr = 1; kbase = 1024; outbase = 96; }

    for (int i = t; i < nr * 128; i += 256) {
        const int r = i >> 7, kk = i & 127;
        s_w[r][kk] = wsrc[r * 1024 + kz * 128 + kk];
    }
    __syncthreads();

    float acc[8];
    #pragma unroll
    for (int r = 0; r < 8; ++r) acc[r] = 0.f;
    const float* cw = comb_w + ((size_t)kbase + kz * 128) * 1024 + j;
    #pragma unroll 4
    for (int k = 0; k < 128; ++k) {
        const float c = cw[(size_t)k * 1024];
        #pragma unroll
        for (int r = 0; r < 8; ++r) acc[r] = fmaf(s_w[r][k], c, acc[r]);
    }

    if (by == 12) {
        atomicAdd(&fused[96 * 1024 + j], acc[0] + (kz == 0 ? comb_b[j] : 0.f));
    } else {
        #pragma unroll
        for (int r = 0; r < 8; ++r) atomicAdd(&fused[(outbase + r) * 1024 + j], acc[r]);
    }
}

// ---------------------------------------------------------------------------
// Kernel 2: compute_h v3 — LDS-tiled skinny GEMMs.
// 1-D grid of 768 blocks: [0,512) h1 path (32 rows/blk), [512,768) h2 path (64 rows/blk).
// Thread tile 2 rows x 4 cols; inner loop is LDS-only (broadcast reads ~free).
// ---------------------------------------------------------------------------
__global__ __launch_bounds__(256) void compute_h(
    const float* __restrict__ encoding,  // [N][512]
    const float* __restrict__ mean,      // [N][1024]
    const float* __restrict__ enc_w1,    // [512][64]
    const float* __restrict__ pol_w1,    // [1024][32]
    const float* __restrict__ pol_b1,    // [32]
    const float* __restrict__ pol_w2,    // [32][32]
    const float* __restrict__ pol_b2,    // [32]
    float* __restrict__ h1h2)            // [N][96]
{
    __shared__ __attribute__((aligned(16))) float smem[64 * PAD + 32 * 32];  // 14.3 KB, shared by both paths
    const int t = threadIdx.x;
    const int bid = blockIdx.x;

    if (bid < 512) {
        // ---- h1: 32 rows x 64 cols. K=512 in 16 tiles of 32.
        float* sA = smem;               // [32][PAD]
        float* sW = smem + 32 * PAD;    // [32][64]  (needs 2048 fl; 32*PAD+2048=3328 <= 3584)
        const long r0 = (long)bid * 32;
        const int tr = t & 15, rr = t >> 4;   // cols tr*4; rows rr*2, rr*2+1
        const int c0 = tr * 4;
        float4 acc0 = {0.f,0.f,0.f,0.f}, acc1 = {0.f,0.f,0.f,0.f};

        for (int kt = 0; kt < 16; ++kt) {
            __syncthreads();
            {   // stage A: 32 rows x 32 fl = 256 f4, one per thread (coalesced 128B/row)
                const int row = t >> 3, seg = t & 7;
                *(float4*)(sA + row * PAD + seg * 4) =
                    *(const float4*)(encoding + (r0 + row) * IN_DIM + kt * 32 + seg * 4);
            }
            #pragma unroll
            for (int i = 0; i < 2; ++i) {   // stage W: 32x64 = 512 f4, fully coalesced
                const int idx = i * 256 + t;
                *(float4*)(sW + idx * 4) = *(const float4*)(enc_w1 + kt * 2048 + idx * 4);
            }
            __syncthreads();
            #pragma unroll
            for (int k4 = 0; k4 < 8; ++k4) {
                const float4 a0 = *(const float4*)(sA + (rr * 2 + 0) * PAD + k4 * 4);
                const float4 a1 = *(const float4*)(sA + (rr * 2 + 1) * PAD + k4 * 4);
                const float4 w0 = *(const float4*)(sW + (k4 * 4 + 0) * 64 + c0);
                const float4 w1 = *(const float4*)(sW + (k4 * 4 + 1) * 64 + c0);
                const float4 w2 = *(const float4*)(sW + (k4 * 4 + 2) * 64 + c0);
                const float4 w3 = *(const float4*)(sW + (k4 * 4 + 3) * 64 + c0);
                acc0.x = fmaf(a0.x, w0.x, acc0.x); acc0.y = fmaf(a0.x, w0.y, acc0.y);
                acc0.z = fmaf(a0.x, w0.z, acc0.z); acc0.w = fmaf(a0.x, w0.w, acc0.w);
                acc0.x = fmaf(a0.y, w1.x, acc0.x); acc0.y = fmaf(a0.y, w1.y, acc0.y);
                acc0.z = fmaf(a0.y, w1.z, acc0.z); acc0.w = fmaf(a0.y, w1.w, acc0.w);
                acc0.x = fmaf(a0.z, w2.x, acc0.x); acc0.y = fmaf(a0.z, w2.y, acc0.y);
                acc0.z = fmaf(a0.z, w2.z, acc0.z); acc0.w = fmaf(a0.z, w2.w, acc0.w);
                acc0.x = fmaf(a0.w, w3.x, acc0.x); acc0.y = fmaf(a0.w, w3.y, acc0.y);
                acc0.z = fmaf(a0.w, w3.z, acc0.z); acc0.w = fmaf(a0.w, w3.w, acc0.w);
                acc1.x = fmaf(a1.x, w0.x, acc1.x); acc1.y = fmaf(a1.x, w0.y, acc1.y);
                acc1.z = fmaf(a1.x, w0.z, acc1.z); acc1.w = fmaf(a1.x, w0.w, acc1.w);
                acc1.x = fmaf(a1.y, w1.x, acc1.x); acc1.y = fmaf(a1.y, w1.y, acc1.y);
                acc1.z = fmaf(a1.y, w1.z, acc1.z); acc1.w = fmaf(a1.y, w1.w, acc1.w);
                acc1.x = fmaf(a1.z, w2.x, acc1.x); acc1.y = fmaf(a1.z, w2.y, acc1.y);
                acc1.z = fmaf(a1.z, w2.z, acc1.z); acc1.w = fmaf(a1.z, w2.w, acc1.w);
                acc1.x = fmaf(a1.w, w3.x, acc1.x); acc1.y = fmaf(a1.w, w3.y, acc1.y);
                acc1.z = fmaf(a1.w, w3.z, acc1.z); acc1.w = fmaf(a1.w, w3.w, acc1.w);
            }
        }
        float4 o0, o1;
        o0.x = fmaxf(acc0.x, 0.f); o0.y = fmaxf(acc0.y, 0.f);
        o0.z = fmaxf(acc0.z, 0.f); o0.w = fmaxf(acc0.w, 0.f);
        o1.x = fmaxf(acc1.x, 0.f); o1.y = fmaxf(acc1.y, 0.f);
        o1.z = fmaxf(acc1.z, 0.f); o1.w = fmaxf(acc1.w, 0.f);
        *(float4*)(h1h2 + (r0 + rr * 2 + 0) * 96 + c0) = o0;
        *(float4*)(h1h2 + (r0 + rr * 2 + 1) * 96 + c0) = o1;
    } else {
        // ---- h2: 64 rows x 32 cols. Layer1 K=1024 in 32 tiles of 32, then layer2 in-block.
        float* sA = smem;               // [64][PAD]
        float* sW = smem + 64 * PAD;    // [32][32]
        const long r0 = (long)(bid - 512) * 64;
        const int tr = t & 7, rr = t >> 3;   // cols tr*4; rows rr*2, rr*2+1
        const int c0 = tr * 4;
        float4 acc0 = {0.f,0.f,0.f,0.f}, acc1 = {0.f,0.f,0.f,0.f};

        for (int kt = 0; kt < 32; ++kt) {
            __syncthreads();
            #pragma unroll
            for (int i = 0; i < 2; ++i) {   // stage A: 64 rows x 32 fl = 512 f4
                const int idx = i * 256 + t;
                const int row = idx >> 3, seg = idx & 7;
                *(float4*)(sA + row * PAD + seg * 4) =
                    *(const float4*)(mean + (r0 + row) * P + kt * 32 + seg * 4);
            }
            // stage W1 k-tile: 32x32 = 256 f4, fully coalesced
            *(float4*)(sW + t * 4) = *(const float4*)(pol_w1 + kt * 1024 + t * 4);
            __syncthreads();
            #pragma unroll
            for (int k4 = 0; k4 < 8; ++k4) {
                const float4 a0 = *(const float4*)(sA + (rr * 2 + 0) * PAD + k4 * 4);
                const float4 a1 = *(const float4*)(sA + (rr * 2 + 1) * PAD + k4 * 4);
                const float4 w0 = *(const float4*)(sW + (k4 * 4 + 0) * 32 + c0);
                const float4 w1 = *(const float4*)(sW + (k4 * 4 + 1) * 32 + c0);
                const float4 w2 = *(const float4*)(sW + (k4 * 4 + 2) * 32 + c0);
                const float4 w3 = *(const float4*)(sW + (k4 * 4 + 3) * 32 + c0);
                acc0.x = fmaf(a0.x, w0.x, acc0.x); acc0.y = fmaf(a0.x, w0.y, acc0.y);
                acc0.z = fmaf(a0.x, w0.z, acc0.z); acc0.w = fmaf(a0.x, w0.w, acc0.w);
                acc0.x = fmaf(a0.y, w1.x, acc0.x); acc0.y = fmaf(a0.y, w1.y, acc0.y);
                acc0.z = fmaf(a0.y, w1.z, acc0.z); acc0.w = fmaf(a0.y, w1.w, acc0.w);
                acc0.x = fmaf(a0.z, w2.x, acc0.x); acc0.y = fmaf(a0.z, w2.y, acc0.y);
                acc0.z = fmaf(a0.z, w2.z, acc0.z); acc0.w = fmaf(a0.z, w2.w, acc0.w);
                acc0.x = fmaf(a0.w, w3.x, acc0.x); acc0.y = fmaf(a0.w, w3.y, acc0.y);
                acc0.z = fmaf(a0.w, w3.z, acc0.z); acc0.w = fmaf(a0.w, w3.w, acc0.w);
                acc1.x = fmaf(a1.x, w0.x, acc1.x); acc1.y = fmaf(a1.x, w0.y, acc1.y);
                acc1.z = fmaf(a1.x, w0.z, acc1.z); acc1.w = fmaf(a1.x, w0.w, acc1.w);
                acc1.x = fmaf(a1.y, w1.x, acc1.x); acc1.y = fmaf(a1.y, w1.y, acc1.y);
                acc1.z = fmaf(a1.y, w1.z, acc1.z); acc1.w = fmaf(a1.y, w1.w, acc1.w);
                acc1.x = fmaf(a1.z, w2.x, acc1.x); acc1.y = fmaf(a1.z, w2.y, acc1.y);
                acc1.z = fmaf(a1.z, w2.z, acc1.z); acc1.w = fmaf(a1.z, w2.w, acc1.w);
                acc1.x = fmaf(a1.w, w3.x, acc1.x); acc1.y = fmaf(a1.w, w3.y, acc1.y);
                acc1.z = fmaf(a1.w, w3.z, acc1.z); acc1.w = fmaf(a1.w, w3.w, acc1.w);
            }
        }
        // t1 = relu(acc + b1) -> sA (reuse); stage W2 -> sW
        __syncthreads();
        {
            const float4 b1 = *(const float4*)(pol_b1 + c0);
            float4 t10, t11;
            t10.x = fmaxf(acc0.x + b1.x, 0.f); t10.y = fmaxf(acc0.y + b1.y, 0.f);
            t10.z = fmaxf(acc0.z + b1.z, 0.f); t10.w = fmaxf(acc0.w + b1.w, 0.f);
            t11.x = fmaxf(acc1.x + b1.x, 0.f); t11.y = fmaxf(acc1.y + b1.y, 0.f);
            t11.z = fmaxf(acc1.z + b1.z, 0.f); t11.w = fmaxf(acc1.w + b1.w, 0.f);
            *(float4*)(sA + (rr * 2 + 0) * PAD + c0) = t10;
            *(float4*)(sA + (rr * 2 + 1) * PAD + c0) = t11;
        }
        *(float4*)(sW + t * 4) = *(const float4*)(pol_w2 + t * 4);
        __syncthreads();

        float4 d0 = {0.f,0.f,0.f,0.f}, d1 = {0.f,0.f,0.f,0.f};
        #pragma unroll
        for (int k4 = 0; k4 < 8; ++k4) {
            const float4 a0 = *(const float4*)(sA + (rr * 2 + 0) * PAD + k4 * 4);
            const float4 a1 = *(const float4*)(sA + (rr * 2 + 1) * PAD + k4 * 4);
            const float4 w0 = *(const float4*)(sW + (k4 * 4 + 0) * 32 + c0);
            const float4 w1 = *(const float4*)(sW + (k4 * 4 + 1) * 32 + c0);
            const float4 w2 = *(const float4*)(sW + (k4 * 4 + 2) * 32 + c0);
            const float4 w3 = *(const float4*)(sW + (k4 * 4 + 3) * 32 + c0);
            d0.x = fmaf(a0.x, w0.x, d0.x); d0.y = fmaf(a0.x, w0.y, d0.y);
            d0.z = fmaf(a0.x, w0.z, d0.z); d0.w = fmaf(a0.x, w0.w, d0.w);
            d0.x = fmaf(a0.y, w1.x, d0.x); d0.y = fmaf(a0.y, w1.y, d0.y);
            d0.z = fmaf(a0.y, w1.z, d0.z); d0.w = fmaf(a0.y, w1.w, d0.w);
            d0.x = fmaf(a0.z, w2.x, d0.x); d0.y = fmaf(a0.z, w2.y, d0.y);
            d0.z = fmaf(a0.z, w2.z, d0.z); d0.w = fmaf(a0.z, w2.w, d0.w);
            d0.x = fmaf(a0.w, w3.x, d0.x); d0.y = fmaf(a0.w, w3.y, d0.y);
            d0.z = fmaf(a0.w, w3.z, d0.z); d0.w = fmaf(a0.w, w3.w, d0.w);
            d1.x = fmaf(a1.x, w0.x, d1.x); d1.y = fmaf(a1.x, w0.y, d1.y);
            d1.z = fmaf(a1.x, w0.z, d1.z); d1.w = fmaf(a1.x, w0.w, d1.w);
            d1.x = fmaf(a1.y, w1.x, d1.x); d1.y = fmaf(a1.y, w1.y, d1.y);
            d1.z = fmaf(a1.y, w1.z, d1.z); d1.w = fmaf(a1.y, w1.w, d1.w);
            d1.x = fmaf(a1.z, w2.x, d1.x); d1.y = fmaf(a1.z, w2.y, d1.y);
            d1.z = fmaf(a1.z, w2.z, d1.z); d1.w = fmaf(a1.z, w2.w, d1.w);
            d1.x = fmaf(a1.w, w3.x, d1.x); d1.y = fmaf(a1.w, w3.y, d1.y);
            d1.z = fmaf(a1.w, w3.z, d1.z); d1.w = fmaf(a1.w, w3.w, d1.w);
        }
        const float4 b2 = *(const float4*)(pol_b2 + c0);
        float4 o0, o1;
        o0.x = fmaxf(d0.x + b2.x, 0.f); o0.y = fmaxf(d0.y + b2.y, 0.f);
        o0.z = fmaxf(d0.z + b2.z, 0.f); o0.w = fmaxf(d0.w + b2.w, 0.f);
        o1.x = fmaxf(d1.x + b2.x, 0.f); o1.y = fmaxf(d1.y + b2.y, 0.f);
        o1.z = fmaxf(d1.z + b2.z, 0.f); o1.w = fmaxf(d1.w + b2.w, 0.f);
        *(float4*)(h1h2 + (r0 + rr * 2 + 0) * 96 + 64 + c0) = o0;
        *(float4*)(h1h2 + (r0 + rr * 2 + 1) * 96 + 64 + c0) = o1;
    }
}

// ---------------------------------------------------------------------------
// Kernel 3: logits + epilogue. Block = 16 rows x 1024 cols; wave owns 4 rows.
// Thread: 4 rows x 16 cols (4 f4 chunks at +0/+256/+512/+768). 16 independent
// global f4 w-loads per k4 iteration (fused is L2-resident). In-wave logprob reduce.
// ---------------------------------------------------------------------------
__global__ __launch_bounds__(256) void logits_epilogue(
    const float* __restrict__ h1h2,    // [N][96]
    const float* __restrict__ fused,   // [97][1024]
    const float* __restrict__ eps,     // [N][1024]
    float* __restrict__ out_sample,    // [N][1024]
    float* __restrict__ out_logprob,   // [N]
    float* __restrict__ out_entropy)   // [N]
{
    __shared__ __attribute__((aligned(16))) float sH[16 * 96];
    const int t = threadIdx.x;
    const long r0 = (long)blockIdx.x * 16;

    {
        const float4* src = (const float4*)(h1h2 + r0 * 96);
        float4* dst = (float4*)sH;
        dst[t] = src[t];
        if (t < 128) dst[256 + t] = src[256 + t];
    }
    __syncthreads();

    const int rg = t >> 6;        // wave id: rows rg*4 .. rg*4+3
    const int cg = t & 63;
    const int j0 = cg * 4;        // col chunks j0 + 256*c4

    float acc[4][16];
    #pragma unroll
    for (int c4 = 0; c4 < 4; ++c4) {
        const float4 b = *(const float4*)(fused + 96 * 1024 + j0 + c4 * 256);
        #pragma unroll
        for (int i = 0; i < 4; ++i) {
            acc[i][c4 * 4 + 0] = b.x; acc[i][c4 * 4 + 1] = b.y;
            acc[i][c4 * 4 + 2] = b.z; acc[i][c4 * 4 + 3] = b.w;
        }
    }

    for (int k4 = 0; k4 < 24; ++k4) {
        float ah[4][4];
        #pragma unroll
        for (int i = 0; i < 4; ++i) {
            const float4 v = *(const float4*)(sH + (rg * 4 + i) * 96 + k4 * 4);
            ah[i][0] = v.x; ah[i][1] = v.y; ah[i][2] = v.z; ah[i][3] = v.w;
        }
        #pragma unroll
        for (int q = 0; q < 4; ++q) {
            #pragma unroll
            for (int c4 = 0; c4 < 4; ++c4) {
                const float4 w = *(const float4*)(fused + (k4 * 4 + q) * 1024 + j0 + c4 * 256);
                #pragma unroll
                for (int i = 0; i < 4; ++i) {
                    acc[i][c4 * 4 + 0] = fmaf(ah[i][q], w.x, acc[i][c4 * 4 + 0]);
                    acc[i][c4 * 4 + 1] = fmaf(ah[i][q], w.y, acc[i][c4 * 4 + 1]);
                    acc[i][c4 * 4 + 2] = fmaf(ah[i][q], w.z, acc[i][c4 * 4 + 2]);
                    acc[i][c4 * 4 + 3] = fmaf(ah[i][q], w.w, acc[i][c4 * 4 + 3]);
                }
            }
        }
    }

    float sq[4] = {0.f, 0.f, 0.f, 0.f};
    #pragma unroll
    for (int i = 0; i < 4; ++i) {
        const long row = r0 + rg * 4 + i;
        #pragma unroll
        for (int c4 = 0; c4 < 4; ++c4) {
            const int j = j0 + c4 * 256;
            const float m0 = 1.f / (1.f + __expf(-acc[i][c4 * 4 + 0]));
            const float m1 = 1.f / (1.f + __expf(-acc[i][c4 * 4 + 1]));
            const float m2 = 1.f / (1.f + __expf(-acc[i][c4 * 4 + 2]));
            const float m3 = 1.f / (1.f + __expf(-acc[i][c4 * 4 + 3]));
            const float4 e = *(const float4*)(eps + row * P + j);
            const float s0 = fminf(fmaxf(fmaf(0.22360679774997896f, e.x, m0), 0.f), 1.f);
            const float s1 = fminf(fmaxf(fmaf(0.22360679774997896f, e.y, m1), 0.f), 1.f);
            const float s2 = fminf(fmaxf(fmaf(0.22360679774997896f, e.z, m2), 0.f), 1.f);
            const float s3 = fminf(fmaxf(fmaf(0.22360679774997896f, e.w, m3), 0.f), 1.f);
            *(float4*)(out_sample + row * P + j) = make_float4(s0, s1, s2, s3);
            const float d0 = s0 - m0, d1 = s1 - m1, d2 = s2 - m2, d3 = s3 - m3;
            sq[i] += fmaf(d0, d0, fmaf(d1, d1, fmaf(d2, d2, d3 * d3)));
        }
    }
    #pragma unroll
    for (int i = 0; i < 4; ++i) {
        float v = sq[i];
        v += __shfl_xor(v, 1);
        v += __shfl_xor(v, 2);
        v += __shfl_xor(v, 4);
        v += __shfl_xor(v, 8);
        v += __shfl_xor(v, 16);
        v += __shfl_xor(v, 32);
        if (cg == 0) {
            out_logprob[r0 + rg * 4 + i] = fmaf(-10.f, v, 592.8218660580586f);
            out_entropy[r0 + rg * 4 + i] = -80.82186605805855f;
        }
    }
}

extern "C" void kernel_launch(void* const* d_in, const int* in_sizes, int n_in,
                              void* d_out, int out_size, void* d_ws, size_t ws_size,
                              hipStream_t stream) {
    const float* encoding = (const float*)d_in[0];
    const float* mean     = (const float*)d_in[1];
    const float* enc_w1   = (const float*)d_in[2];
    const float* enc_w2   = (const float*)d_in[3];
    const float* pol_w1   = (const float*)d_in[4];
    const float* pol_b1   = (const float*)d_in[5];
    const float* pol_w2   = (const float*)d_in[6];
    const float* pol_b2   = (const float*)d_in[7];
    const float* pol_w3   = (const float*)d_in[8];
    const float* pol_b3   = (const float*)d_in[9];
    const float* comb_w   = (const float*)d_in[10];
    const float* comb_b   = (const float*)d_in[11];
    const float* eps      = (const float*)d_in[12];

    float* fused = (float*)d_ws;                          // 97*1024 floats
    float* h1h2  = fused + 97 * 1024;                     // 16384*96 floats
    float* out_sample  = (float*)d_out;
    float* out_logprob = out_sample + (size_t)N_CLIENTS * P;
    float* out_entropy = out_logprob + N_CLIENTS;

    hipMemsetAsync(fused, 0, 97 * 1024 * sizeof(float), stream);

    dim3 gpre(4, 13, 8);
    precompute_fused<<<gpre, 256, 0, stream>>>(enc_w2, pol_w3, pol_b3, comb_w, comb_b, fused);

    compute_h<<<768, 256, 0, stream>>>(encoding, mean, enc_w1, pol_w1, pol_b1,
                                       pol_w2, pol_b2, h1h2);

    logits_epilogue<<<N_CLIENTS / 16, 256, 0, stream>>>(
        h1h2, fused, eps, out_sample, out_logprob, out_entropy);
}

// Round 4
// 271.472 us; speedup vs baseline: 2.2264x; 1.1674x over previous
//
#include <hip/hip_runtime.h>

// HyperNet fused forward, v4.
//   logits = h1 @ (enc_w2 @ comb_top) + h2 @ (pol_w3 @ comb_bot) + (pol_b3 @ comb_bot + comb_b)
//   h1 = relu(enc @ enc_w1) [N,64],  h2 = relu(relu(mean@pol_w1+b1)@pol_w2+b2) [N,32]
//
// R3 post-mortem fixes:
//   logits: acc[4][16] made all 4 waves load identical w (4x redundant, 1.6GB L2). v4 uses
//           acc[16][4] (no redundancy, 397MB) + register-dbuf w prefetch (R2's layout failed
//           only because it had 4 serialized loads in flight).
//   stage1: compute_h staging now register-prefetched one tile ahead (hides ~900cyc HBM);
//           precompute k-split widened to 16 chunks; both merged into one kernel to overlap.

#define N_CLIENTS 16384
#define P 1024
#define IN_DIM 512
#define SPAD 36   // LDS row stride for A tiles

// ---------------------------------------------------------------------------
// stage1: blocks [0,512) h1 | [512,768) h2 | [768,1600) fused-weight precompute
// ---------------------------------------------------------------------------
__global__ __launch_bounds__(256) void stage1(
    const float* __restrict__ encoding,  // [N][512]
    const float* __restrict__ mean,      // [N][1024]
    const float* __restrict__ enc_w1,    // [512][64]
    const float* __restrict__ pol_w1,    // [1024][32]
    const float* __restrict__ pol_b1,    // [32]
    const float* __restrict__ pol_w2,    // [32][32]
    const float* __restrict__ pol_b2,    // [32]
    const float* __restrict__ enc_w2,    // [64][1024]
    const float* __restrict__ pol_w3,    // [32][1024]
    const float* __restrict__ pol_b3,    // [1024]
    const float* __restrict__ comb_w,    // [2048][1024]
    const float* __restrict__ comb_b,    // [1024]
    float* __restrict__ h1h2,            // [N][96]
    float* __restrict__ fused)           // [97][1024] (pre-zeroed)
{
    __shared__ __attribute__((aligned(16))) float smem[64 * SPAD + 32 * 32]; // 13.3 KB
    const int t = threadIdx.x;
    const int bid = blockIdx.x;

    if (bid < 512) {
        // ---- h1: 32 rows x 64 cols, K=512 in 16 tiles of 32, reg-prefetch staging.
        float* sA = smem;                 // [32][SPAD]
        float* sW = smem + 32 * SPAD;     // [32][64]
        const long r0 = (long)bid * 32;
        const int tr = t & 15, rr = t >> 4;
        const int c0 = tr * 4;
        const int arow = t >> 3, aseg = t & 7;
        const float* aSrc = encoding + (r0 + arow) * IN_DIM + aseg * 4;

        float4 aR  = *(const float4*)(aSrc);
        float4 wR0 = *(const float4*)(enc_w1 + t * 4);
        float4 wR1 = *(const float4*)(enc_w1 + (256 + t) * 4);
        float4 acc0 = {0.f,0.f,0.f,0.f}, acc1 = {0.f,0.f,0.f,0.f};

        for (int kt = 0; kt < 16; ++kt) {
            __syncthreads();
            *(float4*)(sA + arow * SPAD + aseg * 4) = aR;
            *(float4*)(sW + t * 4) = wR0;
            *(float4*)(sW + (256 + t) * 4) = wR1;
            __syncthreads();
            if (kt < 15) {   // prefetch next tile while computing this one
                aR  = *(const float4*)(aSrc + (kt + 1) * 32);
                wR0 = *(const float4*)(enc_w1 + (kt + 1) * 2048 + t * 4);
                wR1 = *(const float4*)(enc_w1 + (kt + 1) * 2048 + (256 + t) * 4);
            }
            #pragma unroll
            for (int k4 = 0; k4 < 8; ++k4) {
                const float4 a0 = *(const float4*)(sA + (rr * 2 + 0) * SPAD + k4 * 4);
                const float4 a1 = *(const float4*)(sA + (rr * 2 + 1) * SPAD + k4 * 4);
                const float4 w0 = *(const float4*)(sW + (k4 * 4 + 0) * 64 + c0);
                const float4 w1 = *(const float4*)(sW + (k4 * 4 + 1) * 64 + c0);
                const float4 w2 = *(const float4*)(sW + (k4 * 4 + 2) * 64 + c0);
                const float4 w3 = *(const float4*)(sW + (k4 * 4 + 3) * 64 + c0);
                acc0.x = fmaf(a0.x, w0.x, acc0.x); acc0.y = fmaf(a0.x, w0.y, acc0.y);
                acc0.z = fmaf(a0.x, w0.z, acc0.z); acc0.w = fmaf(a0.x, w0.w, acc0.w);
                acc0.x = fmaf(a0.y, w1.x, acc0.x); acc0.y = fmaf(a0.y, w1.y, acc0.y);
                acc0.z = fmaf(a0.y, w1.z, acc0.z); acc0.w = fmaf(a0.y, w1.w, acc0.w);
                acc0.x = fmaf(a0.z, w2.x, acc0.x); acc0.y = fmaf(a0.z, w2.y, acc0.y);
                acc0.z = fmaf(a0.z, w2.z, acc0.z); acc0.w = fmaf(a0.z, w2.w, acc0.w);
                acc0.x = fmaf(a0.w, w3.x, acc0.x); acc0.y = fmaf(a0.w, w3.y, acc0.y);
                acc0.z = fmaf(a0.w, w3.z, acc0.z); acc0.w = fmaf(a0.w, w3.w, acc0.w);
                acc1.x = fmaf(a1.x, w0.x, acc1.x); acc1.y = fmaf(a1.x, w0.y, acc1.y);
                acc1.z = fmaf(a1.x, w0.z, acc1.z); acc1.w = fmaf(a1.x, w0.w, acc1.w);
                acc1.x = fmaf(a1.y, w1.x, acc1.x); acc1.y = fmaf(a1.y, w1.y, acc1.y);
                acc1.z = fmaf(a1.y, w1.z, acc1.z); acc1.w = fmaf(a1.y, w1.w, acc1.w);
                acc1.x = fmaf(a1.z, w2.x, acc1.x); acc1.y = fmaf(a1.z, w2.y, acc1.y);
                acc1.z = fmaf(a1.z, w2.z, acc1.z); acc1.w = fmaf(a1.z, w2.w, acc1.w);
                acc1.x = fmaf(a1.w, w3.x, acc1.x); acc1.y = fmaf(a1.w, w3.y, acc1.y);
                acc1.z = fmaf(a1.w, w3.z, acc1.z); acc1.w = fmaf(a1.w, w3.w, acc1.w);
            }
        }
        float4 o0, o1;
        o0.x = fmaxf(acc0.x, 0.f); o0.y = fmaxf(acc0.y, 0.f);
        o0.z = fmaxf(acc0.z, 0.f); o0.w = fmaxf(acc0.w, 0.f);
        o1.x = fmaxf(acc1.x, 0.f); o1.y = fmaxf(acc1.y, 0.f);
        o1.z = fmaxf(acc1.z, 0.f); o1.w = fmaxf(acc1.w, 0.f);
        *(float4*)(h1h2 + (r0 + rr * 2 + 0) * 96 + c0) = o0;
        *(float4*)(h1h2 + (r0 + rr * 2 + 1) * 96 + c0) = o1;
    } else if (bid < 768) {
        // ---- h2: 64 rows x 32 cols, K=1024 in 32 tiles of 32, then layer2 in-block.
        float* sA = smem;                 // [64][SPAD]
        float* sW = smem + 64 * SPAD;     // [32][32]
        const long r0 = (long)(bid - 512) * 64;
        const int tr = t & 7, rr = t >> 3;
        const int c0 = tr * 4;
        const int arow0 = t >> 3,        aseg = t & 7;
        const int arow1 = 32 + (t >> 3);
        const float* aSrc0 = mean + (r0 + arow0) * P + aseg * 4;
        const float* aSrc1 = mean + (r0 + arow1) * P + aseg * 4;

        float4 aR0 = *(const float4*)(aSrc0);
        float4 aR1 = *(const float4*)(aSrc1);
        float4 wR  = *(const float4*)(pol_w1 + t * 4);
        float4 acc0 = {0.f,0.f,0.f,0.f}, acc1 = {0.f,0.f,0.f,0.f};

        for (int kt = 0; kt < 32; ++kt) {
            __syncthreads();
            *(float4*)(sA + arow0 * SPAD + aseg * 4) = aR0;
            *(float4*)(sA + arow1 * SPAD + aseg * 4) = aR1;
            *(float4*)(sW + t * 4) = wR;
            __syncthreads();
            if (kt < 31) {
                aR0 = *(const float4*)(aSrc0 + (kt + 1) * 32);
                aR1 = *(const float4*)(aSrc1 + (kt + 1) * 32);
                wR  = *(const float4*)(pol_w1 + (kt + 1) * 1024 + t * 4);
            }
            #pragma unroll
            for (int k4 = 0; k4 < 8; ++k4) {
                const float4 a0 = *(const float4*)(sA + (rr * 2 + 0) * SPAD + k4 * 4);
                const float4 a1 = *(const float4*)(sA + (rr * 2 + 1) * SPAD + k4 * 4);
                const float4 w0 = *(const float4*)(sW + (k4 * 4 + 0) * 32 + c0);
                const float4 w1 = *(const float4*)(sW + (k4 * 4 + 1) * 32 + c0);
                const float4 w2 = *(const float4*)(sW + (k4 * 4 + 2) * 32 + c0);
                const float4 w3 = *(const float4*)(sW + (k4 * 4 + 3) * 32 + c0);
                acc0.x = fmaf(a0.x, w0.x, acc0.x); acc0.y = fmaf(a0.x, w0.y, acc0.y);
                acc0.z = fmaf(a0.x, w0.z, acc0.z); acc0.w = fmaf(a0.x, w0.w, acc0.w);
                acc0.x = fmaf(a0.y, w1.x, acc0.x); acc0.y = fmaf(a0.y, w1.y, acc0.y);
                acc0.z = fmaf(a0.y, w1.z, acc0.z); acc0.w = fmaf(a0.y, w1.w, acc0.w);
                acc0.x = fmaf(a0.z, w2.x, acc0.x); acc0.y = fmaf(a0.z, w2.y, acc0.y);
                acc0.z = fmaf(a0.z, w2.z, acc0.z); acc0.w = fmaf(a0.z, w2.w, acc0.w);
                acc0.x = fmaf(a0.w, w3.x, acc0.x); acc0.y = fmaf(a0.w, w3.y, acc0.y);
                acc0.z = fmaf(a0.w, w3.z, acc0.z); acc0.w = fmaf(a0.w, w3.w, acc0.w);
                acc1.x = fmaf(a1.x, w0.x, acc1.x); acc1.y = fmaf(a1.x, w0.y, acc1.y);
                acc1.z = fmaf(a1.x, w0.z, acc1.z); acc1.w = fmaf(a1.x, w0.w, acc1.w);
                acc1.x = fmaf(a1.y, w1.x, acc1.x); acc1.y = fmaf(a1.y, w1.y, acc1.y);
                acc1.z = fmaf(a1.y, w1.z, acc1.z); acc1.w = fmaf(a1.y, w1.w, acc1.w);
                acc1.x = fmaf(a1.z, w2.x, acc1.x); acc1.y = fmaf(a1.z, w2.y, acc1.y);
                acc1.z = fmaf(a1.z, w2.z, acc1.z); acc1.w = fmaf(a1.z, w2.w, acc1.w);
                acc1.x = fmaf(a1.w, w3.x, acc1.x); acc1.y = fmaf(a1.w, w3.y, acc1.y);
                acc1.z = fmaf(a1.w, w3.z, acc1.z); acc1.w = fmaf(a1.w, w3.w, acc1.w);
            }
        }
        // t1 = relu(acc+b1) -> sA; stage pol_w2 -> sW
        __syncthreads();
        {
            const float4 b1 = *(const float4*)(pol_b1 + c0);
            float4 t10, t11;
            t10.x = fmaxf(acc0.x + b1.x, 0.f); t10.y = fmaxf(acc0.y + b1.y, 0.f);
            t10.z = fmaxf(acc0.z + b1.z, 0.f); t10.w = fmaxf(acc0.w + b1.w, 0.f);
            t11.x = fmaxf(acc1.x + b1.x, 0.f); t11.y = fmaxf(acc1.y + b1.y, 0.f);
            t11.z = fmaxf(acc1.z + b1.z, 0.f); t11.w = fmaxf(acc1.w + b1.w, 0.f);
            *(float4*)(sA + (rr * 2 + 0) * SPAD + c0) = t10;
            *(float4*)(sA + (rr * 2 + 1) * SPAD + c0) = t11;
        }
        *(float4*)(sW + t * 4) = *(const float4*)(pol_w2 + t * 4);
        __syncthreads();

        float4 d0 = {0.f,0.f,0.f,0.f}, d1 = {0.f,0.f,0.f,0.f};
        #pragma unroll
        for (int k4 = 0; k4 < 8; ++k4) {
            const float4 a0 = *(const float4*)(sA + (rr * 2 + 0) * SPAD + k4 * 4);
            const float4 a1 = *(const float4*)(sA + (rr * 2 + 1) * SPAD + k4 * 4);
            const float4 w0 = *(const float4*)(sW + (k4 * 4 + 0) * 32 + c0);
            const float4 w1 = *(const float4*)(sW + (k4 * 4 + 1) * 32 + c0);
            const float4 w2 = *(const float4*)(sW + (k4 * 4 + 2) * 32 + c0);
            const float4 w3 = *(const float4*)(sW + (k4 * 4 + 3) * 32 + c0);
            d0.x = fmaf(a0.x, w0.x, d0.x); d0.y = fmaf(a0.x, w0.y, d0.y);
            d0.z = fmaf(a0.x, w0.z, d0.z); d0.w = fmaf(a0.x, w0.w, d0.w);
            d0.x = fmaf(a0.y, w1.x, d0.x); d0.y = fmaf(a0.y, w1.y, d0.y);
            d0.z = fmaf(a0.y, w1.z, d0.z); d0.w = fmaf(a0.y, w1.w, d0.w);
            d0.x = fmaf(a0.z, w2.x, d0.x); d0.y = fmaf(a0.z, w2.y, d0.y);
            d0.z = fmaf(a0.z, w2.z, d0.z); d0.w = fmaf(a0.z, w2.w, d0.w);
            d0.x = fmaf(a0.w, w3.x, d0.x); d0.y = fmaf(a0.w, w3.y, d0.y);
            d0.z = fmaf(a0.w, w3.z, d0.z); d0.w = fmaf(a0.w, w3.w, d0.w);
            d1.x = fmaf(a1.x, w0.x, d1.x); d1.y = fmaf(a1.x, w0.y, d1.y);
            d1.z = fmaf(a1.x, w0.z, d1.z); d1.w = fmaf(a1.x, w0.w, d1.w);
            d1.x = fmaf(a1.y, w1.x, d1.x); d1.y = fmaf(a1.y, w1.y, d1.y);
            d1.z = fmaf(a1.y, w1.z, d1.z); d1.w = fmaf(a1.y, w1.w, d1.w);
            d1.x = fmaf(a1.z, w2.x, d1.x); d1.y = fmaf(a1.z, w2.y, d1.y);
            d1.z = fmaf(a1.z, w2.z, d1.z); d1.w = fmaf(a1.z, w2.w, d1.w);
            d1.x = fmaf(a1.w, w3.x, d1.x); d1.y = fmaf(a1.w, w3.y, d1.y);
            d1.z = fmaf(a1.w, w3.z, d1.z); d1.w = fmaf(a1.w, w3.w, d1.w);
        }
        const float4 b2 = *(const float4*)(pol_b2 + c0);
        float4 o0, o1;
        o0.x = fmaxf(d0.x + b2.x, 0.f); o0.y = fmaxf(d0.y + b2.y, 0.f);
        o0.z = fmaxf(d0.z + b2.z, 0.f); o0.w = fmaxf(d0.w + b2.w, 0.f);
        o1.x = fmaxf(d1.x + b2.x, 0.f); o1.y = fmaxf(d1.y + b2.y, 0.f);
        o1.z = fmaxf(d1.z + b2.z, 0.f); o1.w = fmaxf(d1.w + b2.w, 0.f);
        *(float4*)(h1h2 + (r0 + rr * 2 + 0) * 96 + 64 + c0) = o0;
        *(float4*)(h1h2 + (r0 + rr * 2 + 1) * 96 + 64 + c0) = o1;
    } else {
        // ---- fused-weight precompute: pid -> (j-chunk, row-group, k-chunk of 64)
        const int pid = bid - 768;          // [0, 832)
        const int jc = pid & 3;
        const int rest = pid >> 2;          // [0, 208)
        const int by = rest % 13;
        const int kz = rest / 13;           // [0, 16)
        const int j = jc * 256 + t;

        const float* wsrc; int nr, kbase, outbase;
        if (by < 8)       { wsrc = enc_w2 + by * 8 * 1024;        nr = 8; kbase = 0;    outbase = by * 8; }
        else if (by < 12) { wsrc = pol_w3 + (by - 8) * 8 * 1024;  nr = 8; kbase = 1024; outbase = 64 + (by - 8) * 8; }
        else              { wsrc = pol_b3;                        nr = 1; kbase = 1024; outbase = 96; }

        float* s_w = smem;   // [8][64]
        for (int i = t; i < nr * 64; i += 256)
            s_w[i] = wsrc[(i >> 6) * 1024 + kz * 64 + (i & 63)];
        __syncthreads();

        float acc[8];
        #pragma unroll
        for (int r = 0; r < 8; ++r) acc[r] = 0.f;
        const float* cw = comb_w + ((size_t)kbase + kz * 64) * 1024 + j;
        #pragma unroll 4
        for (int k = 0; k < 64; ++k) {
            const float c = cw[(size_t)k * 1024];
            #pragma unroll
            for (int r = 0; r < 8; ++r) acc[r] = fmaf(s_w[r * 64 + k], c, acc[r]);
        }
        if (by == 12) {
            atomicAdd(&fused[96 * 1024 + j], acc[0] + (kz == 0 ? comb_b[j] : 0.f));
        } else {
            #pragma unroll
            for (int r = 0; r < 8; ++r) atomicAdd(&fused[(outbase + r) * 1024 + j], acc[r]);
        }
    }
}

// ---------------------------------------------------------------------------
// logits + epilogue. Block = 16 rows x 1024 cols; thread = 16 rows x 4 contiguous
// cols (j0 = t*4, no w redundancy in block). w register-dbuf one k4 ahead.
// ---------------------------------------------------------------------------
__global__ __launch_bounds__(256) void logits_epilogue(
    const float* __restrict__ h1h2,    // [N][96]
    const float* __restrict__ fused,   // [97][1024]
    const float* __restrict__ eps,     // [N][1024]
    float* __restrict__ out_sample,    // [N][1024]
    float* __restrict__ out_logprob,   // [N]
    float* __restrict__ out_entropy)   // [N]
{
    __shared__ __attribute__((aligned(16))) float sH[16 * 96];   // 6 KB
    __shared__ float s_red[16][4];
    const int t = threadIdx.x;
    const long r0 = (long)blockIdx.x * 16;

    {
        const float4* src = (const float4*)(h1h2 + r0 * 96);
        float4* dst = (float4*)sH;
        dst[t] = src[t];
        if (t < 128) dst[256 + t] = src[256 + t];
    }
    __syncthreads();

    const int j0 = t * 4;
    const float* fj = fused + j0;

    float4 acc[16];
    {
        const float4 b = *(const float4*)(fj + 96 * 1024);
        #pragma unroll
        for (int r = 0; r < 16; ++r) acc[r] = b;
    }

    float4 wc0 = *(const float4*)(fj);
    float4 wc1 = *(const float4*)(fj + 1024);
    float4 wc2 = *(const float4*)(fj + 2048);
    float4 wc3 = *(const float4*)(fj + 3072);

    for (int k4 = 0; k4 < 24; ++k4) {
        const int kn = (k4 < 23) ? (k4 + 1) * 4 : 92;   // last-iter prefetch re-reads row 92 (discarded)
        const float* fn = fj + (size_t)kn * 1024;
        const float4 wn0 = *(const float4*)(fn);
        const float4 wn1 = *(const float4*)(fn + 1024);
        const float4 wn2 = *(const float4*)(fn + 2048);
        const float4 wn3 = *(const float4*)(fn + 3072);
        #pragma unroll
        for (int r = 0; r < 16; ++r) {
            const float4 h = *(const float4*)(sH + r * 96 + k4 * 4);  // broadcast
            acc[r].x = fmaf(h.x, wc0.x, acc[r].x);
            acc[r].y = fmaf(h.x, wc0.y, acc[r].y);
            acc[r].z = fmaf(h.x, wc0.z, acc[r].z);
            acc[r].w = fmaf(h.x, wc0.w, acc[r].w);
            acc[r].x = fmaf(h.y, wc1.x, acc[r].x);
            acc[r].y = fmaf(h.y, wc1.y, acc[r].y);
            acc[r].z = fmaf(h.y, wc1.z, acc[r].z);
            acc[r].w = fmaf(h.y, wc1.w, acc[r].w);
            acc[r].x = fmaf(h.z, wc2.x, acc[r].x);
            acc[r].y = fmaf(h.z, wc2.y, acc[r].y);
            acc[r].z = fmaf(h.z, wc2.z, acc[r].z);
            acc[r].w = fmaf(h.z, wc2.w, acc[r].w);
            acc[r].x = fmaf(h.w, wc3.x, acc[r].x);
            acc[r].y = fmaf(h.w, wc3.y, acc[r].y);
            acc[r].z = fmaf(h.w, wc3.z, acc[r].z);
            acc[r].w = fmaf(h.w, wc3.w, acc[r].w);
        }
        wc0 = wn0; wc1 = wn1; wc2 = wn2; wc3 = wn3;
    }

    float sq[16];
    const float* ep = eps + r0 * P + j0;
    float* sp = out_sample + r0 * P + j0;
    #pragma unroll
    for (int r = 0; r < 16; ++r) {
        const float m0 = 1.f / (1.f + __expf(-acc[r].x));
        const float m1 = 1.f / (1.f + __expf(-acc[r].y));
        const float m2 = 1.f / (1.f + __expf(-acc[r].z));
        const float m3 = 1.f / (1.f + __expf(-acc[r].w));
        const float4 e = *(const float4*)(ep + r * P);
        const float s0 = fminf(fmaxf(fmaf(0.22360679774997896f, e.x, m0), 0.f), 1.f);
        const float s1 = fminf(fmaxf(fmaf(0.22360679774997896f, e.y, m1), 0.f), 1.f);
        const float s2 = fminf(fmaxf(fmaf(0.22360679774997896f, e.z, m2), 0.f), 1.f);
        const float s3 = fminf(fmaxf(fmaf(0.22360679774997896f, e.w, m3), 0.f), 1.f);
        *(float4*)(sp + r * P) = make_float4(s0, s1, s2, s3);
        const float d0 = s0 - m0, d1 = s1 - m1, d2 = s2 - m2, d3 = s3 - m3;
        sq[r] = fmaf(d0, d0, fmaf(d1, d1, fmaf(d2, d2, d3 * d3)));
    }
    #pragma unroll
    for (int r = 0; r < 16; ++r) {
        float v = sq[r];
        v += __shfl_xor(v, 1);
        v += __shfl_xor(v, 2);
        v += __shfl_xor(v, 4);
        v += __shfl_xor(v, 8);
        v += __shfl_xor(v, 16);
        v += __shfl_xor(v, 32);
        if ((t & 63) == 0) s_red[r][t >> 6] = v;
    }
    __syncthreads();
    if (t < 16) {
        const float v = s_red[t][0] + s_red[t][1] + s_red[t][2] + s_red[t][3];
        out_logprob[r0 + t] = fmaf(-10.f, v, 592.8218660580586f);
        out_entropy[r0 + t] = -80.82186605805855f;
    }
}

extern "C" void kernel_launch(void* const* d_in, const int* in_sizes, int n_in,
                              void* d_out, int out_size, void* d_ws, size_t ws_size,
                              hipStream_t stream) {
    const float* encoding = (const float*)d_in[0];
    const float* mean     = (const float*)d_in[1];
    const float* enc_w1   = (const float*)d_in[2];
    const float* enc_w2   = (const float*)d_in[3];
    const float* pol_w1   = (const float*)d_in[4];
    const float* pol_b1   = (const float*)d_in[5];
    const float* pol_w2   = (const float*)d_in[6];
    const float* pol_b2   = (const float*)d_in[7];
    const float* pol_w3   = (const float*)d_in[8];
    const float* pol_b3   = (const float*)d_in[9];
    const float* comb_w   = (const float*)d_in[10];
    const float* comb_b   = (const float*)d_in[11];
    const float* eps      = (const float*)d_in[12];

    float* fused = (float*)d_ws;                          // 97*1024 floats
    float* h1h2  = fused + 97 * 1024;                     // 16384*96 floats
    float* out_sample  = (float*)d_out;
    float* out_logprob = out_sample + (size_t)N_CLIENTS * P;
    float* out_entropy = out_logprob + N_CLIENTS;

    hipMemsetAsync(fused, 0, 97 * 1024 * sizeof(float), stream);

    stage1<<<1600, 256, 0, stream>>>(encoding, mean, enc_w1, pol_w1, pol_b1,
                                     pol_w2, pol_b2, enc_w2, pol_w3, pol_b3,
                                     comb_w, comb_b, h1h2, fused);

    logits_epilogue<<<N_CLIENTS / 16, 256, 0, stream>>>(
        h1h2, fused, eps, out_sample, out_logprob, out_entropy);
}